// Round 6
// baseline (392.862 us; speedup 1.0000x reference)
//
#include <hip/hip_runtime.h>
#include <hip/hip_bf16.h>
#include <stdint.h>

// Problem constants (fixed by setup_inputs)
#define BB 4
#define TT 4096
#define CC 2048
#define HH 16
#define DD 128
#define MM (BB*TT)   // 16384
#define KK CC        // 2048
#define NNx CC       // 2048
#define NTP 16       // K / 128 (tile-pairs of 2x64)

#define NCH 128
#define CHL (TT/NCH) // 32

typedef unsigned short u16;
typedef unsigned int   u32;
typedef __bf16 bf16x8 __attribute__((ext_vector_type(8)));
typedef float  f32x4  __attribute__((ext_vector_type(4)));

__device__ __forceinline__ float bf2f(u32 lo) {
  union { u32 u; float f; } z; z.u = lo << 16; return z.f;
}
__device__ __forceinline__ u16 f2bf(float f) {
  union { float f; u32 u; } z; z.f = f;
  u32 u = z.u;
  return (u16)((u + 0x7FFFu + ((u >> 16) & 1u)) >> 16); // RNE
}
__device__ __forceinline__ void unpack8(uint4 v, float* a) {
  a[0]=bf2f(v.x&0xffffu); a[1]=bf2f(v.x>>16);
  a[2]=bf2f(v.y&0xffffu); a[3]=bf2f(v.y>>16);
  a[4]=bf2f(v.z&0xffffu); a[5]=bf2f(v.z>>16);
  a[6]=bf2f(v.w&0xffffu); a[7]=bf2f(v.w>>16);
}

// ---------------- f32 -> bf16 convert (vectorized, 8 elem/thread) ----------
__global__ void cvt_f32_bf16(const float* __restrict__ in, u16* __restrict__ out, long n) {
  long i = ((long)blockIdx.x * blockDim.x + threadIdx.x) * 8;
  if (i >= n) return;
  float4 v0 = *(const float4*)(in + i);
  float4 v1 = *(const float4*)(in + i + 4);
  uint4 o;
  o.x = (u32)f2bf(v0.x) | ((u32)f2bf(v0.y) << 16);
  o.y = (u32)f2bf(v0.z) | ((u32)f2bf(v0.w) << 16);
  o.z = (u32)f2bf(v1.x) | ((u32)f2bf(v1.y) << 16);
  o.w = (u32)f2bf(v1.z) | ((u32)f2bf(v1.w) << 16);
  *(uint4*)(out + i) = o;
}

__device__ __forceinline__ void gload16(const void* g, void* l) {
  __builtin_amdgcn_global_load_lds(
      (__attribute__((address_space(1))) void*)g,
      (__attribute__((address_space(3))) void*)l, 16, 0, 0);
}

// ---------------- GEMM: C = A(M,K) * B(N,K)^T, 256x256 tile, 8-phase -------
// Proven: swizzled LDS 4-slot ring, setprio, XCD-chunked remap, vmcnt(8) at
// even phases (4-phase float). r6: REGISTER DOUBLE-BUFFER the fragment
// loads — phase p prefetches phase p+1's av/bv after barrier #1, MFMAs on
// the regs loaded last phase. LDS pipe now overlaps the MFMA burst.
// Prefetch coverage: each prefetched slot is covered by the even-phase
// vmcnt(8) immediately before it (s1@P2, s2@P4, s3@P6, s0'@P8, prologue->s0).
// Prefetch slot != same-phase stage slot in all 8 phases (disjoint).
// Same (slot,mh) MFMA sequence as r2-r5 -> bit-identical output.
// EPI=1: fused scan1 chunk partial sums (per-32-row column sums of bf16^2).
template<int OUTF32, int EPI>
__global__ __launch_bounds__(512, 2)
void gemm256(const u16* __restrict__ A, const u16* __restrict__ Bm,
             float* __restrict__ Cf, u16* __restrict__ Cb,
             float* __restrict__ S1)
{
  __shared__ u16 As[4][8192];   // 4 x 16KB
  __shared__ u16 Bs[4][8192];   // 4 x 16KB   (total 128 KB)
  const int tid  = threadIdx.x;
  const int wid  = tid >> 6;
  const int lane = tid & 63;
  const int wm = wid >> 2, wn = wid & 3;     // 2 x 4 wave grid
  const int fr = lane & 15, kg = lane >> 4;
  // XCD-chunked bijective remap (nwg=512, 8 XCDs, XCD = orig%8)
  const int orig = blockIdx.x;
  const int nid  = ((orig & 7) << 6) | (orig >> 3);
  const int m0 = (nid >> 3) * 256;
  const int n0 = (nid & 7) * 256;

  const int srow = tid >> 2;                       // 0..127 (j adds 128)
  const int sc   = (tid & 3) ^ ((srow >> 1) & 3);  // pre-swizzled source chunk
  const u16* gA0 = A  + (size_t)(m0 + srow) * KK + sc * 8;
  const u16* gA1 = gA0 + (size_t)128 * KK;
  const u16* gB0 = Bm + (size_t)(n0 + srow) * KK + sc * 8;
  const u16* gB1 = gB0 + (size_t)128 * KK;
  const int ldst0 = wid * 512;
  const int ldst1 = 4096 + wid * 512;

  const int cs    = kg ^ ((fr >> 1) & 3);
  const int abase = (wm * 128 + fr) * 32 + cs * 8;
  const int bbase = (wn * 64  + fr) * 32 + cs * 8;

  f32x4 acc[8][4];
  #pragma unroll
  for (int i = 0; i < 8; ++i)
    #pragma unroll
    for (int j = 0; j < 4; ++j) acc[i][j] = (f32x4){0.f,0.f,0.f,0.f};

  auto stA = [&](int slot, int ko) {
    gload16(gA0 + ko, &As[slot][ldst0]);
    gload16(gA1 + ko, &As[slot][ldst1]);
  };
  auto stB = [&](int slot, int ko) {
    gload16(gB0 + ko, &Bs[slot][ldst0]);
    gload16(gB1 + ko, &Bs[slot][ldst1]);
  };

#define LDA4(dst, SLOT, MH)                                                   \
    _Pragma("unroll")                                                         \
    for (int f = 0; f < 4; ++f)                                               \
      dst[f] = *(const bf16x8*)&As[SLOT][abase + ((MH)*64 + f*16)*32];
#define LDB4(dst, SLOT)                                                       \
    _Pragma("unroll")                                                         \
    for (int f = 0; f < 4; ++f)                                               \
      dst[f] = *(const bf16x8*)&Bs[SLOT][bbase + f*16*32];
#define MF16(AV, BV, MH)                                                      \
    __builtin_amdgcn_s_setprio(1);                                            \
    _Pragma("unroll")                                                         \
    for (int f = 0; f < 4; ++f)                                               \
      _Pragma("unroll")                                                       \
      for (int n = 0; n < 4; ++n)                                             \
        acc[(MH)*4+f][n] = __builtin_amdgcn_mfma_f32_16x16x32_bf16(          \
            AV[f], BV[n], acc[(MH)*4+f][n], 0, 0, 0);                         \
    __builtin_amdgcn_s_setprio(0);                                            \
    __builtin_amdgcn_s_barrier();

  // prologue: stage s0,s1,s2 (12 loads); vmcnt(8) -> s0 landed; prefetch P1
  stA(0, 0);  stB(0, 0);
  stA(1, 32); stB(1, 32);
  stA(2, 64); stB(2, 64);
  asm volatile("s_waitcnt vmcnt(8)" ::: "memory");
  __builtin_amdgcn_s_barrier();

  bf16x8 a0[4], a1[4], b0[4], b1[4];
  LDA4(a0, 0, 0)
  LDB4(b0, 0)

  for (int it = 0; it < NTP; ++it) {
    const int kb = it * 128;
    const bool nx = (it + 1 < NTP);
    // P1: consume (s0,mh0)=a0,b0 | stage 3A | prefetch a1<-(s0,mh1)
    stA(3, kb + 96);
    __builtin_amdgcn_s_barrier();
    LDA4(a1, 0, 1)
    MF16(a0, b0, 0)
    // P2: consume (s0,mh1)=a1,b0 | stage 3B | W | prefetch a0<-(s1,0), b1<-(s1)
    stB(3, kb + 96);
    asm volatile("s_waitcnt vmcnt(8)" ::: "memory");
    __builtin_amdgcn_s_barrier();
    LDA4(a0, 1, 0)
    LDB4(b1, 1)
    MF16(a1, b0, 1)
    // P3: consume (s1,mh0)=a0,b1 | stage 0A' | prefetch a1<-(s1,1)
    if (nx) stA(0, kb + 128);
    __builtin_amdgcn_s_barrier();
    LDA4(a1, 1, 1)
    MF16(a0, b1, 0)
    // P4: consume (s1,mh1)=a1,b1 | stage 0B' | W | prefetch a0<-(s2,0), b0<-(s2)
    if (nx) stB(0, kb + 128);
    asm volatile("s_waitcnt vmcnt(8)" ::: "memory");
    __builtin_amdgcn_s_barrier();
    LDA4(a0, 2, 0)
    LDB4(b0, 2)
    MF16(a1, b1, 1)
    // P5: consume (s2,mh0)=a0,b0 | stage 1A' | prefetch a1<-(s2,1)
    if (nx) stA(1, kb + 160);
    __builtin_amdgcn_s_barrier();
    LDA4(a1, 2, 1)
    MF16(a0, b0, 0)
    // P6: consume (s2,mh1)=a1,b0 | stage 1B' | W | prefetch a0<-(s3,0), b1<-(s3)
    if (nx) stB(1, kb + 160);
    asm volatile("s_waitcnt vmcnt(8)" ::: "memory");
    __builtin_amdgcn_s_barrier();
    LDA4(a0, 3, 0)
    LDB4(b1, 3)
    MF16(a1, b0, 1)
    // P7: consume (s3,mh0)=a0,b1 | stage 2A' | prefetch a1<-(s3,1)
    if (nx) stA(2, kb + 192);
    __builtin_amdgcn_s_barrier();
    LDA4(a1, 3, 1)
    MF16(a0, b1, 0)
    // P8: consume (s3,mh1)=a1,b1 | stage 2B' | W | prefetch a0<-(s0',0), b0<-(s0')
    if (nx) stB(2, kb + 192);
    asm volatile("s_waitcnt vmcnt(8)" ::: "memory");
    __builtin_amdgcn_s_barrier();
    LDA4(a0, 0, 0)
    LDB4(b0, 0)
    MF16(a1, b1, 1)
  }
#undef LDA4
#undef LDB4
#undef MF16

  // C/D layout: col = lane&15, row = (lane>>4)*4 + reg   [m89/m91]
  const int row0 = m0 + wm * 128 + kg * 4;
  const int col0 = n0 + wn * 64 + fr;
  if (OUTF32) {
    #pragma unroll
    for (int mf = 0; mf < 8; ++mf)
      #pragma unroll
      for (int nf = 0; nf < 4; ++nf)
        #pragma unroll
        for (int r = 0; r < 4; ++r)
          Cf[(size_t)(row0 + mf*16 + r) * NNx + col0 + nf*16] = acc[mf][nf][r];
  } else {
    float csum[4][4];
    #pragma unroll
    for (int p = 0; p < 4; ++p)
      #pragma unroll
      for (int nf = 0; nf < 4; ++nf) csum[p][nf] = 0.f;
    #pragma unroll
    for (int mf = 0; mf < 8; ++mf)
      #pragma unroll
      for (int nf = 0; nf < 4; ++nf)
        #pragma unroll
        for (int r = 0; r < 4; ++r) {
          u16 hb = f2bf(acc[mf][nf][r]);
          Cb[(size_t)(row0 + mf*16 + r) * NNx + col0 + nf*16] = hb;
          if (EPI) { float av_ = bf2f(hb); csum[mf>>1][nf] += av_ * av_; }
        }
    if (EPI) {
      // reduce over kg (rows kg*4+r) and store per 32-row chunk
      const int b   = m0 >> 12;                 // m0 / TT
      const int ch0 = ((m0 & (TT-1)) >> 5) + wm * 4;
      #pragma unroll
      for (int p = 0; p < 4; ++p)
        #pragma unroll
        for (int nf = 0; nf < 4; ++nf) {
          float v = csum[p][nf];
          v += __shfl_xor(v, 16, 64);
          v += __shfl_xor(v, 32, 64);
          if (kg == 0)
            S1[(size_t)(ch0 + p) * (BB*CC) + b * CC + col0 + nf*16] = v;
        }
    }
  }
}

// ---------------- exclusive scan over chunk axis ---------------------------
// S layout: [NCH][BB*CC]; one thread per (b,c) column, coalesced.
__global__ void excl_big(float* __restrict__ p) {
  const int g = blockIdx.x * 256 + threadIdx.x;   // 0..8191
  float run = 0.f;
  for (int ch = 0; ch < NCH; ++ch) {
    float v = p[(size_t)ch * (BB*CC) + g];
    p[(size_t)ch * (BB*CC) + g] = run;
    run += v;
  }
}
__global__ void excl_sp(float* __restrict__ p) {
  const int g = threadIdx.x;                       // 0..63 (b*HH+h)
  float run = 0.f;
  for (int ch = 0; ch < NCH; ++ch) {
    float v = p[ch * (BB*HH) + g];
    p[ch * (BB*HH) + g] = run;
    run += v;
  }
}

// ---------------- Pass C: scan1_main + head softmax + scan2_partial --------
// block = (chunk, b); 256 threads cover all 2048 channels (8 per thread).
__global__ __launch_bounds__(256)
void pass_c(const u16* __restrict__ w, float* __restrict__ S,
            float* __restrict__ SP, float* __restrict__ Pi,
            const float* __restrict__ temp, const float* __restrict__ dbias)
{
  __shared__ float sm[2][HH];
  const int ch = blockIdx.x, b = blockIdx.y;
  const int tid = threadIdx.x;
  const int h = tid >> 4;
  const int t0 = ch * CHL;
  const u16* wrow = w + ((size_t)b*TT + t0) * CC + tid*8;
  float* Srow = S + (size_t)ch * (BB*CC) + b * CC + tid*8;
  float c0[8], s2[8];
  #pragma unroll
  for (int j = 0; j < 8; ++j) { c0[j] = Srow[j]; s2[j] = 0.f; }
  const float th = temp[h];
  const float* db = dbias + (size_t)h * TT + t0;
  float sp = 0.f;
  uint4 v = *(const uint4*)wrow;
  for (int t = 0; t < CHL; ++t) {
    uint4 vn = v;
    if (t + 1 < CHL) vn = *(const uint4*)(wrow + (size_t)(t+1) * CC);
    float a2[8];
    { float a[8]; unpack8(v, a);
      #pragma unroll
      for (int j = 0; j < 8; ++j) a2[j] = a[j]*a[j]; }
    float val = 0.f;
    #pragma unroll
    for (int j = 0; j < 8; ++j) {
      c0[j] += a2[j];
      val += a2[j] * __builtin_amdgcn_rcpf(fmaxf(c0[j], 1e-12f));
    }
    val += __shfl_xor(val, 1, 64);
    val += __shfl_xor(val, 2, 64);
    val += __shfl_xor(val, 4, 64);
    val += __shfl_xor(val, 8, 64);
    const float tmp = th * (val + (float)DD * db[t]);
    if ((tid & 15) == 0) sm[t & 1][h] = tmp;
    __syncthreads();
    float m = -1e30f;
    #pragma unroll
    for (int hh = 0; hh < HH; ++hh) m = fmaxf(m, sm[t & 1][hh]);
    float ssum = 0.f;
    #pragma unroll
    for (int hh = 0; hh < HH; ++hh) ssum += __expf(sm[t & 1][hh] - m);
    const float pi = __expf(sm[t & 1][h] - m) * __builtin_amdgcn_rcpf(ssum);
    sp += pi;
    #pragma unroll
    for (int j = 0; j < 8; ++j) s2[j] += a2[j] * pi;
    if ((tid & 15) == 0) Pi[((size_t)b*TT + t0 + t) * HH + h] = pi;
    v = vn;
  }
  #pragma unroll
  for (int j = 0; j < 8; ++j) Srow[j] = s2[j];
  if ((tid & 15) == 0) SP[ch * (BB*HH) + b * HH + h] = sp;
}

// ---------------- Pass D: scan2_main -> ymid (bf16, (B,T,C)) ---------------
__global__ __launch_bounds__(256)
void pass_d(const u16* __restrict__ w, const float* __restrict__ S2,
            const float* __restrict__ SP, const float* __restrict__ Pi,
            u16* __restrict__ ymid)
{
  const int ch = blockIdx.x, b = blockIdx.y;
  const int tid = threadIdx.x;
  const int h = tid >> 4;
  const int t0 = ch * CHL;
  const u16* wrow = w + ((size_t)b*TT + t0) * CC + tid*8;
  u16* yrow = ymid + ((size_t)b*TT + t0) * CC + tid*8;
  const float* Srow = S2 + (size_t)ch * (BB*CC) + b * CC + tid*8;
  float c2[8];
  #pragma unroll
  for (int j = 0; j < 8; ++j) c2[j] = Srow[j];
  float cp = SP[ch * (BB*HH) + b * HH + h];
  const float* prow = Pi + ((size_t)b*TT + t0) * HH + h;
  uint4 v = *(const uint4*)wrow;
  for (int t = 0; t < CHL; ++t) {
    uint4 vn = v;
    if (t + 1 < CHL) vn = *(const uint4*)(wrow + (size_t)(t+1) * CC);
    const float pi = prow[(size_t)t * HH];
    cp += pi;
    const float invp = __builtin_amdgcn_rcpf(cp + 1e-8f);
    float a[8]; unpack8(v, a);
    float y[8];
    #pragma unroll
    for (int j = 0; j < 8; ++j) {
      const float a2 = a[j]*a[j];
      c2[j] += a2 * pi;
      const float d = c2[j] * invp;
      y[j] = -(a[j] * pi) * __builtin_amdgcn_rcpf(1.f + d);
    }
    uint4 o;
    o.x = (u32)f2bf(y[0]) | ((u32)f2bf(y[1]) << 16);
    o.y = (u32)f2bf(y[2]) | ((u32)f2bf(y[3]) << 16);
    o.z = (u32)f2bf(y[4]) | ((u32)f2bf(y[5]) << 16);
    o.w = (u32)f2bf(y[6]) | ((u32)f2bf(y[7]) << 16);
    *(uint4*)(yrow + (size_t)t * CC) = o;
    v = vn;
  }
}

// ---------------- launch ----------------------------------------------------
extern "C" void kernel_launch(void* const* d_in, const int* in_sizes, int n_in,
                              void* d_out, int out_size, void* d_ws, size_t ws_size,
                              hipStream_t stream) {
  const float* x     = (const float*)d_in[0];
  const float* Wa    = (const float*)d_in[1];
  const float* Wp    = (const float*)d_in[2];
  const float* temp  = (const float*)d_in[3];
  const float* dbias = (const float*)d_in[4];
  float* out = (float*)d_out;

  char* ws = (char*)d_ws;
  u16*  xb   = (u16*)(ws);                      // 67,108,864 B
  u16*  Wab  = (u16*)(ws + 67108864);           //  8,388,608 (dead after GEMM1)
  u16*  Wpb  = (u16*)(ws + 75497472);           //  8,388,608
  u16*  wbuf = (u16*)(ws + 83886080);           // 67,108,864 -> ends 150,994,944
  float* S1  = (float*)(ws + 150994944);        //  4,194,304 (S2 reuses in-place)
  float* SP  = (float*)(ws + 155189248);        //     32,768 -> ends 155,222,016
  float* Pi  = (float*)(ws + 67108864);         //  1,048,576 (overlays dead Wab)
  u16*  ymid = xb;                              // xb dead after GEMM1

  // 1) convert inputs to bf16
  cvt_f32_bf16<<<(MM*(long)KK)/8/256, 256, 0, stream>>>(x,  xb,  (long)MM*KK);
  cvt_f32_bf16<<<((long)CC*CC)/8/256, 256, 0, stream>>>(Wa, Wab, (long)CC*CC);
  cvt_f32_bf16<<<((long)CC*CC)/8/256, 256, 0, stream>>>(Wp, Wpb, (long)CC*CC);

  // 2) w = x @ Wa^T (bf16) + fused scan1 chunk partial sums -> S1
  gemm256<0,1><<<512, 512, 0, stream>>>(xb, Wab, nullptr, wbuf, S1);

  // 3) scan1 offsets
  excl_big<<<(BB*CC)/256, 256, 0, stream>>>(S1);

  // 4) fused scan1_main + softmax + scan2_partial (writes Pi, S2=S1, SP)
  dim3 gc(NCH, BB);
  pass_c<<<gc, 256, 0, stream>>>(wbuf, S1, SP, Pi, temp, dbias);

  // 5) scan2 offsets
  excl_big<<<(BB*CC)/256, 256, 0, stream>>>(S1);
  excl_sp<<<1, 64, 0, stream>>>(SP);

  // 6) scan2 main -> ymid
  pass_d<<<gc, 256, 0, stream>>>(wbuf, S1, SP, Pi, ymid);

  // 7) out = y_mid @ Wp^T (f32 out)
  gemm256<1,0><<<512, 512, 0, stream>>>(ymid, Wpb, out, nullptr, nullptr);
}

// Round 7
// 383.148 us; speedup vs baseline: 1.0254x; 1.0254x over previous
//
#include <hip/hip_runtime.h>
#include <hip/hip_bf16.h>
#include <stdint.h>

// Problem constants (fixed by setup_inputs)
#define BB 4
#define TT 4096
#define CC 2048
#define HH 16
#define DD 128
#define MM (BB*TT)   // 16384
#define KK CC        // 2048
#define NNx CC       // 2048
#define NTP 16       // K / 128 (tile-pairs of 2x64)

#define NCH 128
#define CHL (TT/NCH) // 32

typedef unsigned short u16;
typedef unsigned int   u32;
typedef __bf16 bf16x8 __attribute__((ext_vector_type(8)));
typedef float  f32x4  __attribute__((ext_vector_type(4)));

__device__ __forceinline__ float bf2f(u32 lo) {
  union { u32 u; float f; } z; z.u = lo << 16; return z.f;
}
__device__ __forceinline__ u16 f2bf(float f) {
  union { float f; u32 u; } z; z.f = f;
  u32 u = z.u;
  return (u16)((u + 0x7FFFu + ((u >> 16) & 1u)) >> 16); // RNE
}
__device__ __forceinline__ void unpack8(uint4 v, float* a) {
  a[0]=bf2f(v.x&0xffffu); a[1]=bf2f(v.x>>16);
  a[2]=bf2f(v.y&0xffffu); a[3]=bf2f(v.y>>16);
  a[4]=bf2f(v.z&0xffffu); a[5]=bf2f(v.z>>16);
  a[6]=bf2f(v.w&0xffffu); a[7]=bf2f(v.w>>16);
}

// ---------------- f32 -> bf16 convert (vectorized, 8 elem/thread) ----------
__global__ void cvt_f32_bf16(const float* __restrict__ in, u16* __restrict__ out, long n) {
  long i = ((long)blockIdx.x * blockDim.x + threadIdx.x) * 8;
  if (i >= n) return;
  float4 v0 = *(const float4*)(in + i);
  float4 v1 = *(const float4*)(in + i + 4);
  uint4 o;
  o.x = (u32)f2bf(v0.x) | ((u32)f2bf(v0.y) << 16);
  o.y = (u32)f2bf(v0.z) | ((u32)f2bf(v0.w) << 16);
  o.z = (u32)f2bf(v1.x) | ((u32)f2bf(v1.y) << 16);
  o.w = (u32)f2bf(v1.z) | ((u32)f2bf(v1.w) << 16);
  *(uint4*)(out + i) = o;
}

__device__ __forceinline__ void gload16(const void* g, void* l) {
  __builtin_amdgcn_global_load_lds(
      (__attribute__((address_space(1))) void*)g,
      (__attribute__((address_space(3))) void*)l, 16, 0, 0);
}

// ---------------- GEMM: C = A(M,K) * B(N,K)^T, 256x256 tile, 4-phase -------
// r7: 4 phases/iter (full K-tile-64 x mh-half = 32 MFMA each), barriers ONLY
// at the two stage points (4/iter, was 16). No barrier between a phase's
// MFMA and the next phase's ds_reads -> matrix pipe and LDS pipe overlap
// across waves. Hazard proof:
//  WAR: stages (P2/P4) preceded by lgkmcnt(0)+barrier; every wave's earlier
//       reads of the target pair are drained before it reaches that barrier.
//  RAW: P1's pair drained by P4-prev vmcnt(8)+bar (P4's own 8 loads newest);
//       P3's pair by P2-this vmcnt(8)+bar. Last iter: no new stage issued ->
//       use vmcnt(0) there instead (else P3 reads in-flight data).
// MFMA order per acc element is k-ascending as before -> bit-identical C.
// EPI=1: fused scan1 chunk partial sums (per-32-row column sums of bf16^2).
template<int OUTF32, int EPI>
__global__ __launch_bounds__(512, 2)
void gemm256(const u16* __restrict__ A, const u16* __restrict__ Bm,
             float* __restrict__ Cf, u16* __restrict__ Cb,
             float* __restrict__ S1)
{
  __shared__ u16 As[4][8192];   // 4 x 16KB  (pair 0,1 = even tile; 2,3 = odd)
  __shared__ u16 Bs[4][8192];   // 4 x 16KB   (total 128 KB)
  const int tid  = threadIdx.x;
  const int wid  = tid >> 6;
  const int lane = tid & 63;
  const int wm = wid >> 2, wn = wid & 3;     // 2 x 4 wave grid
  const int fr = lane & 15, kg = lane >> 4;
  // XCD-chunked bijective remap (nwg=512, 8 XCDs, XCD = orig%8)
  const int orig = blockIdx.x;
  const int nid  = ((orig & 7) << 6) | (orig >> 3);
  const int m0 = (nid >> 3) * 256;
  const int n0 = (nid & 7) * 256;

  const int srow = tid >> 2;                       // 0..127 (j adds 128)
  const int sc   = (tid & 3) ^ ((srow >> 1) & 3);  // pre-swizzled source chunk
  const u16* gA0 = A  + (size_t)(m0 + srow) * KK + sc * 8;
  const u16* gA1 = gA0 + (size_t)128 * KK;
  const u16* gB0 = Bm + (size_t)(n0 + srow) * KK + sc * 8;
  const u16* gB1 = gB0 + (size_t)128 * KK;
  const int ldst0 = wid * 512;
  const int ldst1 = 4096 + wid * 512;

  const int cs    = kg ^ ((fr >> 1) & 3);
  const int abase = (wm * 128 + fr) * 32 + cs * 8;
  const int bbase = (wn * 64  + fr) * 32 + cs * 8;

  f32x4 acc[8][4];
  #pragma unroll
  for (int i = 0; i < 8; ++i)
    #pragma unroll
    for (int j = 0; j < 4; ++j) acc[i][j] = (f32x4){0.f,0.f,0.f,0.f};

  auto stA = [&](int slot, int ko) {
    gload16(gA0 + ko, &As[slot][ldst0]);
    gload16(gA1 + ko, &As[slot][ldst1]);
  };
  auto stB = [&](int slot, int ko) {
    gload16(gB0 + ko, &Bs[slot][ldst0]);
    gload16(gB1 + ko, &Bs[slot][ldst1]);
  };

#define LDA4S(dst, SLOT, MH)                                                  \
    _Pragma("unroll")                                                         \
    for (int f = 0; f < 4; ++f)                                               \
      dst[f] = *(const bf16x8*)&As[SLOT][abase + ((MH)*64 + f*16)*32];
#define LDB4S(dst, SLOT)                                                      \
    _Pragma("unroll")                                                         \
    for (int f = 0; f < 4; ++f)                                               \
      dst[f] = *(const bf16x8*)&Bs[SLOT][bbase + f*16*32];
#define MFHALF(AV, BV, MH)                                                    \
    _Pragma("unroll")                                                         \
    for (int f = 0; f < 4; ++f)                                               \
      _Pragma("unroll")                                                       \
      for (int n = 0; n < 4; ++n)                                             \
        acc[(MH)*4+f][n] = __builtin_amdgcn_mfma_f32_16x16x32_bf16(          \
            AV[f], BV[n], acc[(MH)*4+f][n], 0, 0, 0);

  // prologue: stage tile0 -> (0,1), tile1 -> (2,3); drain tile0; barrier.
  stA(0, 0);  stA(1, 32); stB(0, 0);  stB(1, 32);
  stA(2, 64); stA(3, 96); stB(2, 64); stB(3, 96);
  asm volatile("s_waitcnt vmcnt(8)" ::: "memory");
  __builtin_amdgcn_s_barrier();

  bf16x8 ak0[4], ak1[4], bk0[4], bk1[4];

  for (int it = 0; it < NTP; ++it) {
    const int kb = it * 128;
    const bool nx = (it + 1 < NTP);
    // ---- P1: tile e (pair 0,1), mh0. reads 16, MFMA 32, no barrier ----
    LDA4S(ak0, 0, 0) LDA4S(ak1, 1, 0)
    LDB4S(bk0, 0)    LDB4S(bk1, 1)
    __builtin_amdgcn_s_setprio(1);
    MFHALF(ak0, bk0, 0) MFHALF(ak1, bk1, 0)
    __builtin_amdgcn_s_setprio(0);
    // ---- P2: tile e, mh1. reads 8 | lgkm0+bar | stage e+2 | vmcnt+bar | MFMA
    LDA4S(ak0, 0, 1) LDA4S(ak1, 1, 1)
    asm volatile("s_waitcnt lgkmcnt(0)" ::: "memory");
    __builtin_amdgcn_s_barrier();
    if (nx) {
      stA(0, kb + 128); stA(1, kb + 160);
      stB(0, kb + 128); stB(1, kb + 160);
      asm volatile("s_waitcnt vmcnt(8)" ::: "memory");
    } else {
      asm volatile("s_waitcnt vmcnt(0)" ::: "memory");
    }
    __builtin_amdgcn_s_barrier();
    __builtin_amdgcn_s_setprio(1);
    MFHALF(ak0, bk0, 1) MFHALF(ak1, bk1, 1)
    __builtin_amdgcn_s_setprio(0);
    // ---- P3: tile o (pair 2,3), mh0. reads 16, MFMA 32, no barrier ----
    LDA4S(ak0, 2, 0) LDA4S(ak1, 3, 0)
    LDB4S(bk0, 2)    LDB4S(bk1, 3)
    __builtin_amdgcn_s_setprio(1);
    MFHALF(ak0, bk0, 0) MFHALF(ak1, bk1, 0)
    __builtin_amdgcn_s_setprio(0);
    // ---- P4: tile o, mh1. reads 8 | lgkm0+bar | stage o+2 | vmcnt+bar | MFMA
    LDA4S(ak0, 2, 1) LDA4S(ak1, 3, 1)
    asm volatile("s_waitcnt lgkmcnt(0)" ::: "memory");
    __builtin_amdgcn_s_barrier();
    if (nx) {
      stA(2, kb + 192); stA(3, kb + 224);
      stB(2, kb + 192); stB(3, kb + 224);
      asm volatile("s_waitcnt vmcnt(8)" ::: "memory");
    } else {
      asm volatile("s_waitcnt vmcnt(0)" ::: "memory");
    }
    __builtin_amdgcn_s_barrier();
    __builtin_amdgcn_s_setprio(1);
    MFHALF(ak0, bk0, 1) MFHALF(ak1, bk1, 1)
    __builtin_amdgcn_s_setprio(0);
  }
#undef LDA4S
#undef LDB4S
#undef MFHALF

  // C/D layout: col = lane&15, row = (lane>>4)*4 + reg   [m89/m91]
  const int row0 = m0 + wm * 128 + kg * 4;
  const int col0 = n0 + wn * 64 + fr;
  if (OUTF32) {
    #pragma unroll
    for (int mf = 0; mf < 8; ++mf)
      #pragma unroll
      for (int nf = 0; nf < 4; ++nf)
        #pragma unroll
        for (int r = 0; r < 4; ++r)
          Cf[(size_t)(row0 + mf*16 + r) * NNx + col0 + nf*16] = acc[mf][nf][r];
  } else {
    float csum[4][4];
    #pragma unroll
    for (int p = 0; p < 4; ++p)
      #pragma unroll
      for (int nf = 0; nf < 4; ++nf) csum[p][nf] = 0.f;
    #pragma unroll
    for (int mf = 0; mf < 8; ++mf)
      #pragma unroll
      for (int nf = 0; nf < 4; ++nf)
        #pragma unroll
        for (int r = 0; r < 4; ++r) {
          u16 hb = f2bf(acc[mf][nf][r]);
          Cb[(size_t)(row0 + mf*16 + r) * NNx + col0 + nf*16] = hb;
          if (EPI) { float av_ = bf2f(hb); csum[mf>>1][nf] += av_ * av_; }
        }
    if (EPI) {
      // reduce over kg (rows kg*4+r) and store per 32-row chunk
      const int b   = m0 >> 12;                 // m0 / TT
      const int ch0 = ((m0 & (TT-1)) >> 5) + wm * 4;
      #pragma unroll
      for (int p = 0; p < 4; ++p)
        #pragma unroll
        for (int nf = 0; nf < 4; ++nf) {
          float v = csum[p][nf];
          v += __shfl_xor(v, 16, 64);
          v += __shfl_xor(v, 32, 64);
          if (kg == 0)
            S1[(size_t)(ch0 + p) * (BB*CC) + b * CC + col0 + nf*16] = v;
        }
    }
  }
}

// ---------------- exclusive scan over chunk axis ---------------------------
// S layout: [NCH][BB*CC]; one thread per (b,c) column, coalesced.
__global__ void excl_big(float* __restrict__ p) {
  const int g = blockIdx.x * 256 + threadIdx.x;   // 0..8191
  float run = 0.f;
  for (int ch = 0; ch < NCH; ++ch) {
    float v = p[(size_t)ch * (BB*CC) + g];
    p[(size_t)ch * (BB*CC) + g] = run;
    run += v;
  }
}
__global__ void excl_sp(float* __restrict__ p) {
  const int g = threadIdx.x;                       // 0..63 (b*HH+h)
  float run = 0.f;
  for (int ch = 0; ch < NCH; ++ch) {
    float v = p[ch * (BB*HH) + g];
    p[ch * (BB*HH) + g] = run;
    run += v;
  }
}

// ---------------- Pass C: scan1_main + head softmax + scan2_partial --------
// block = (chunk, b); 256 threads cover all 2048 channels (8 per thread).
__global__ __launch_bounds__(256)
void pass_c(const u16* __restrict__ w, float* __restrict__ S,
            float* __restrict__ SP, float* __restrict__ Pi,
            const float* __restrict__ temp, const float* __restrict__ dbias)
{
  __shared__ float sm[2][HH];
  const int ch = blockIdx.x, b = blockIdx.y;
  const int tid = threadIdx.x;
  const int h = tid >> 4;
  const int t0 = ch * CHL;
  const u16* wrow = w + ((size_t)b*TT + t0) * CC + tid*8;
  float* Srow = S + (size_t)ch * (BB*CC) + b * CC + tid*8;
  float c0[8], s2[8];
  #pragma unroll
  for (int j = 0; j < 8; ++j) { c0[j] = Srow[j]; s2[j] = 0.f; }
  const float th = temp[h];
  const float* db = dbias + (size_t)h * TT + t0;
  float sp = 0.f;
  uint4 v = *(const uint4*)wrow;
  for (int t = 0; t < CHL; ++t) {
    uint4 vn = v;
    if (t + 1 < CHL) vn = *(const uint4*)(wrow + (size_t)(t+1) * CC);
    float a2[8];
    { float a[8]; unpack8(v, a);
      #pragma unroll
      for (int j = 0; j < 8; ++j) a2[j] = a[j]*a[j]; }
    float val = 0.f;
    #pragma unroll
    for (int j = 0; j < 8; ++j) {
      c0[j] += a2[j];
      val += a2[j] * __builtin_amdgcn_rcpf(fmaxf(c0[j], 1e-12f));
    }
    val += __shfl_xor(val, 1, 64);
    val += __shfl_xor(val, 2, 64);
    val += __shfl_xor(val, 4, 64);
    val += __shfl_xor(val, 8, 64);
    const float tmp = th * (val + (float)DD * db[t]);
    if ((tid & 15) == 0) sm[t & 1][h] = tmp;
    __syncthreads();
    float m = -1e30f;
    #pragma unroll
    for (int hh = 0; hh < HH; ++hh) m = fmaxf(m, sm[t & 1][hh]);
    float ssum = 0.f;
    #pragma unroll
    for (int hh = 0; hh < HH; ++hh) ssum += __expf(sm[t & 1][hh] - m);
    const float pi = __expf(sm[t & 1][h] - m) * __builtin_amdgcn_rcpf(ssum);
    sp += pi;
    #pragma unroll
    for (int j = 0; j < 8; ++j) s2[j] += a2[j] * pi;
    if ((tid & 15) == 0) Pi[((size_t)b*TT + t0 + t) * HH + h] = pi;
    v = vn;
  }
  #pragma unroll
  for (int j = 0; j < 8; ++j) Srow[j] = s2[j];
  if ((tid & 15) == 0) SP[ch * (BB*HH) + b * HH + h] = sp;
}

// ---------------- Pass D: scan2_main -> ymid (bf16, (B,T,C)) ---------------
__global__ __launch_bounds__(256)
void pass_d(const u16* __restrict__ w, const float* __restrict__ S2,
            const float* __restrict__ SP, const float* __restrict__ Pi,
            u16* __restrict__ ymid)
{
  const int ch = blockIdx.x, b = blockIdx.y;
  const int tid = threadIdx.x;
  const int h = tid >> 4;
  const int t0 = ch * CHL;
  const u16* wrow = w + ((size_t)b*TT + t0) * CC + tid*8;
  u16* yrow = ymid + ((size_t)b*TT + t0) * CC + tid*8;
  const float* Srow = S2 + (size_t)ch * (BB*CC) + b * CC + tid*8;
  float c2[8];
  #pragma unroll
  for (int j = 0; j < 8; ++j) c2[j] = Srow[j];
  float cp = SP[ch * (BB*HH) + b * HH + h];
  const float* prow = Pi + ((size_t)b*TT + t0) * HH + h;
  uint4 v = *(const uint4*)wrow;
  for (int t = 0; t < CHL; ++t) {
    uint4 vn = v;
    if (t + 1 < CHL) vn = *(const uint4*)(wrow + (size_t)(t+1) * CC);
    const float pi = prow[(size_t)t * HH];
    cp += pi;
    const float invp = __builtin_amdgcn_rcpf(cp + 1e-8f);
    float a[8]; unpack8(v, a);
    float y[8];
    #pragma unroll
    for (int j = 0; j < 8; ++j) {
      const float a2 = a[j]*a[j];
      c2[j] += a2 * pi;
      const float d = c2[j] * invp;
      y[j] = -(a[j] * pi) * __builtin_amdgcn_rcpf(1.f + d);
    }
    uint4 o;
    o.x = (u32)f2bf(y[0]) | ((u32)f2bf(y[1]) << 16);
    o.y = (u32)f2bf(y[2]) | ((u32)f2bf(y[3]) << 16);
    o.z = (u32)f2bf(y[4]) | ((u32)f2bf(y[5]) << 16);
    o.w = (u32)f2bf(y[6]) | ((u32)f2bf(y[7]) << 16);
    *(uint4*)(yrow + (size_t)t * CC) = o;
    v = vn;
  }
}

// ---------------- launch ----------------------------------------------------
extern "C" void kernel_launch(void* const* d_in, const int* in_sizes, int n_in,
                              void* d_out, int out_size, void* d_ws, size_t ws_size,
                              hipStream_t stream) {
  const float* x     = (const float*)d_in[0];
  const float* Wa    = (const float*)d_in[1];
  const float* Wp    = (const float*)d_in[2];
  const float* temp  = (const float*)d_in[3];
  const float* dbias = (const float*)d_in[4];
  float* out = (float*)d_out;

  char* ws = (char*)d_ws;
  u16*  xb   = (u16*)(ws);                      // 67,108,864 B
  u16*  Wab  = (u16*)(ws + 67108864);           //  8,388,608 (dead after GEMM1)
  u16*  Wpb  = (u16*)(ws + 75497472);           //  8,388,608
  u16*  wbuf = (u16*)(ws + 83886080);           // 67,108,864 -> ends 150,994,944
  float* S1  = (float*)(ws + 150994944);        //  4,194,304 (S2 reuses in-place)
  float* SP  = (float*)(ws + 155189248);        //     32,768 -> ends 155,222,016
  float* Pi  = (float*)(ws + 67108864);         //  1,048,576 (overlays dead Wab)
  u16*  ymid = xb;                              // xb dead after GEMM1

  // 1) convert inputs to bf16
  cvt_f32_bf16<<<(MM*(long)KK)/8/256, 256, 0, stream>>>(x,  xb,  (long)MM*KK);
  cvt_f32_bf16<<<((long)CC*CC)/8/256, 256, 0, stream>>>(Wa, Wab, (long)CC*CC);
  cvt_f32_bf16<<<((long)CC*CC)/8/256, 256, 0, stream>>>(Wp, Wpb, (long)CC*CC);

  // 2) w = x @ Wa^T (bf16) + fused scan1 chunk partial sums -> S1
  gemm256<0,1><<<512, 512, 0, stream>>>(xb, Wab, nullptr, wbuf, S1);

  // 3) scan1 offsets
  excl_big<<<(BB*CC)/256, 256, 0, stream>>>(S1);

  // 4) fused scan1_main + softmax + scan2_partial (writes Pi, S2=S1, SP)
  dim3 gc(NCH, BB);
  pass_c<<<gc, 256, 0, stream>>>(wbuf, S1, SP, Pi, temp, dbias);

  // 5) scan2 offsets
  excl_big<<<(BB*CC)/256, 256, 0, stream>>>(S1);
  excl_sp<<<1, 64, 0, stream>>>(SP);

  // 6) scan2 main -> ymid
  pass_d<<<gc, 256, 0, stream>>>(wbuf, S1, SP, Pi, ymid);

  // 7) out = y_mid @ Wp^T (f32 out)
  gemm256<1,0><<<512, 512, 0, stream>>>(ymid, Wpb, out, nullptr, nullptr);
}